// Round 1
// 690.591 us; speedup vs baseline: 1.0234x; 1.0234x over previous
//
#include <hip/hip_runtime.h>
#include <math.h>

#define B_ 8192
#define F_ 16
#define V_ 50000
#define D_ 32
#define NE_ 3
#define EOD_ 512
#define M1_ 512
#define M2_ 256
#define M3_ 128
#define BE_ ((size_t)B_ * EOD_)

typedef __attribute__((ext_vector_type(8))) short short8;
typedef __attribute__((ext_vector_type(4))) float floatx4;
typedef __attribute__((ext_vector_type(4))) unsigned short us4;

__device__ __forceinline__ unsigned short f2bf(float f) {
    union { float f; unsigned u; } v; v.f = f;
    unsigned r = v.u + 0x7FFF + ((v.u >> 16) & 1);
    return (unsigned short)(r >> 16);
}
__device__ __forceinline__ float bf2f(unsigned short h) {
    union { unsigned u; float f; } v; v.u = (unsigned)h << 16;
    return v.f;
}
// async global->LDS, 16B per lane; LDS dest must be wave-uniform base + lane*16
__device__ __forceinline__ void gld16(const void* g, void* l) {
    __builtin_amdgcn_global_load_lds(
        (const __attribute__((address_space(1))) unsigned int*)g,
        (__attribute__((address_space(3))) unsigned int*)l, 16, 0, 0);
}
// load 3 bf16x8 slices (stride BE_), sum in f32, store 16B to LDS
__device__ __forceinline__ void sum3st(const unsigned short* p, unsigned short* l) {
    uint4 a = *(const uint4*)p;
    uint4 b = *(const uint4*)(p + BE_);
    uint4 c = *(const uint4*)(p + 2 * BE_);
    const unsigned short* pa = (const unsigned short*)&a;
    const unsigned short* pb = (const unsigned short*)&b;
    const unsigned short* pc = (const unsigned short*)&c;
    unsigned short r[8];
    #pragma unroll
    for (int j = 0; j < 8; j++) r[j] = f2bf(bf2f(pa[j]) + bf2f(pb[j]) + bf2f(pc[j]));
    *(uint4*)l = *(uint4*)r;
}

// ---------------- embedding gather (fp32 tables -> bf16 es) ----------------
__global__ __launch_bounds__(256) void gather_k(const int* __restrict__ x,
    const float* __restrict__ tables, unsigned short* __restrict__ esb)
{
    int gid = blockIdx.x * 256 + threadIdx.x;   // NE*B*F*4 threads, 8 elems each
    int d8 = gid & 3;
    int f  = (gid >> 2) & 15;
    int b  = (gid >> 6) & (B_ - 1);
    int e  = gid >> 19;
    int idx = x[b * F_ + f] + f * V_;
    const float4* src = (const float4*)(tables + ((size_t)e * F_ * V_ + idx) * D_) + d8 * 2;
    float4 v0 = src[0], v1 = src[1];
    unsigned short o[8];
    o[0] = f2bf(v0.x); o[1] = f2bf(v0.y); o[2] = f2bf(v0.z); o[3] = f2bf(v0.w);
    o[4] = f2bf(v1.x); o[5] = f2bf(v1.y); o[6] = f2bf(v1.z); o[7] = f2bf(v1.w);
    unsigned short* dst = esb + ((size_t)e * B_ + b) * EOD_ + f * D_ + d8 * 8;
    *(uint4*)dst = *(uint4*)o;
}

// ------------- weight transpose+convert: fp32 W[K][N] -> bf16 Wt[N][K] -------------
__global__ __launch_bounds__(256) void wtrans12_k(const float* __restrict__ crossW,
    const float* __restrict__ mlp1W, unsigned short* __restrict__ Wt)
{
    __shared__ float tile[32][33];
    int bn = blockIdx.x * 32, bk = blockIdx.y * 32;
    int mat = blockIdx.z;
    const float* Wm = (mat < 9) ? crossW + (size_t)mat * 512 * 512
                                : mlp1W + (size_t)(mat - 9) * 512 * 512;
    unsigned short* Wtm = Wt + (size_t)mat * 512 * 512;
    int tx = threadIdx.x & 31, ty = threadIdx.x >> 5;   // 32 x 8
    #pragma unroll
    for (int i = 0; i < 32; i += 8)
        tile[ty + i][tx] = Wm[(size_t)(bk + ty + i) * 512 + bn + tx];
    __syncthreads();
    #pragma unroll
    for (int i = 0; i < 32; i += 8)
        Wtm[(size_t)(bn + ty + i) * 512 + bk + tx] = f2bf(tile[tx][ty + i]);
}

__global__ __launch_bounds__(256) void wtrans_k(const float* __restrict__ W,
    unsigned short* __restrict__ Wt, int K, int N)
{
    __shared__ float tile[32][33];
    int bn = blockIdx.x * 32, bk = blockIdx.y * 32;
    int tx = threadIdx.x & 31, ty = threadIdx.x >> 5;
    #pragma unroll
    for (int i = 0; i < 32; i += 8)
        tile[ty + i][tx] = W[(size_t)(bk + ty + i) * N + bn + tx];
    __syncthreads();
    #pragma unroll
    for (int i = 0; i < 32; i += 8)
        Wt[(size_t)(bn + ty + i) * K + bk + tx] = f2bf(tile[tx][ty + i]);
}

// ---------------- aux device paths (fused as extra z-blocks into GEMMs) ----------------
// pair Gram accumulation (bf16 in, fp32 atomic accum); ablk in [0,768)
__device__ void pairsum_dev(const unsigned short* es, float* m, int ablk, int t,
                            void* smemv)
{
    const int pi[3] = {1, 2, 2};
    const int pj[3] = {0, 0, 1};
    int pk = ablk % 48, by = ablk / 48;
    int pair = pk >> 4, k = pk & 15;
    const unsigned short* Ei = es + (size_t)pi[pair] * BE_ + k * D_;
    const unsigned short* Ej = es + (size_t)pj[pair] * BE_ + k * D_;
    int b0 = by * (B_ / 16);

    float (*sa)[32] = (float(*)[32])smemv;
    float (*sb)[32] = sa + 8;
    int d = t >> 3, e4 = (t & 7) * 4;
    int lr = t >> 5, lc = t & 31;
    float a0 = 0, a1 = 0, a2 = 0, a3 = 0;

    for (int bb = b0; bb < b0 + B_ / 16; bb += 8) {
        __syncthreads();
        sa[lr][lc] = bf2f(Ei[(size_t)(bb + lr) * EOD_ + lc]);
        sb[lr][lc] = bf2f(Ej[(size_t)(bb + lr) * EOD_ + lc]);
        __syncthreads();
        #pragma unroll
        for (int s2 = 0; s2 < 8; s2++) {
            float avv = sa[s2][d];
            float4 bvv = *(const float4*)&sb[s2][e4];
            a0 += avv * bvv.x; a1 += avv * bvv.y;
            a2 += avv * bvv.z; a3 += avv * bvv.w;
        }
    }
    float* dst = m + (size_t)pk * 1024 + d * 32 + e4;
    atomicAdd(dst + 0, a0); atomicAdd(dst + 1, a1);
    atomicAdd(dst + 2, a2); atomicAdd(dst + 3, a3);
}

// 32x32 singular values: one-sided Jacobi, one wave per matrix, register-resident
__device__ void svd_dev(const float* mg, float* sv, int ablk, int t, void* smemv)
{
    if (ablk >= 48 || t >= 64) return;
    int mat = ablk;
    int l = t;
    int col = l & 31, half = l >> 5;
    const float* src = mg + (size_t)mat * 1024 + half * 16 * 32 + col;
    float a[16];
    #pragma unroll
    for (int j = 0; j < 16; j++) a[j] = src[j * 32];

    for (int sweep = 0; sweep < 6; sweep++) {
        for (int r = 0; r < 31; r++) {
            int partner, isp;
            if (col == 31) { partner = r; isp = 1; }
            else {
                int u = col - r; if (u < 0) u += 31;
                if (u == 0) { partner = 31; isp = 0; }
                else {
                    int v = 2 * r - col; v %= 31; if (v < 0) v += 31;
                    partner = v;
                    isp = (u <= 15) ? 1 : 0;
                }
            }
            int plane = half * 32 + partner;
            float b[16];
            #pragma unroll
            for (int j = 0; j < 16; j++) b[j] = __shfl(a[j], plane, 64);
            float own = 0.f, cross = 0.f, par = 0.f;
            #pragma unroll
            for (int j = 0; j < 16; j++) {
                own   += a[j] * a[j];
                cross += a[j] * b[j];
                par   += b[j] * b[j];
            }
            own   += __shfl_xor(own, 32);
            cross += __shfl_xor(cross, 32);
            par   += __shfl_xor(par, 32);
            float app = isp ? own : par;
            float aqq = isp ? par : own;
            float c = 1.f, s = 0.f;
            if (fabsf(cross) > 1e-12f) {
                float tau = (aqq - app) / (2.f * cross);
                float tt = (tau >= 0.f) ? 1.f / (tau + sqrtf(1.f + tau * tau))
                                        : 1.f / (tau - sqrtf(1.f + tau * tau));
                c = rsqrtf(1.f + tt * tt); s = tt * c;
            }
            float sgn = isp ? -s : s;
            #pragma unroll
            for (int j = 0; j < 16; j++) a[j] = c * a[j] + sgn * b[j];
        }
    }

    float nn = 0.f;
    #pragma unroll
    for (int j = 0; j < 16; j++) nn += a[j] * a[j];
    nn += __shfl_xor(nn, 32);
    float v = sqrtf(nn);

    float* ev = (float*)smemv;
    if (half == 0) ev[col] = v;
    // single wave: LDS ops complete in program order
    if (half == 0) {
        int rank = 0;
        for (int o2 = 0; o2 < 32; o2++) {
            float w = ev[o2];
            if (w > v || (w == v && o2 < col)) rank++;
        }
        sv[(size_t)mat * 32 + rank] = v;
    }
}

// reg loss reduction (256 threads, one block)
__device__ void reg_dev(const float* sv, float* outf, int ablk, int t, void* smemv)
{
    if (ablk != 0) return;
    float* red = (float*)smemv;
    float val = 0.f;
    if (t < 96) {
        int p = t >> 5, d = t & 31;
        float s = 0;
        #pragma unroll
        for (int k = 0; k < 16; k++) s += sv[(size_t)(p * 16 + k) * 32 + d];
        s *= (1.f / 16.f);
        val = s * s;
    }
    red[t] = val; __syncthreads();
    for (int off = 128; off > 0; off >>= 1) {
        if (t < off) red[t] += red[t + off];
        __syncthreads();
    }
    if (t == 0) outf[B_] = 0.01f * red[0] / 96.f;
}

// ---------------- bf16 MFMA GEMM, 128x128 tile, BK=32, z-batched ----------------
// Swapped-operand MFMA: lane holds 4 CONSECUTIVE COLS of one row -> us4 epilogue.
// MODE 0: v = x0*v + xl  (cross layer)
// MODE 1: v = relu(v)/3  (mlp1 slices)
// MODE 2: v = relu(v)    (W1)
// MODE 3: relu -> LDS -> per-row dot with W3 + sigmoid -> outf (W2+final fused)
// ASUM 1: A-staging sums 3 bf16 slices (stride BE_) instead of gld16
// AUX: 0 none, 1 pairsum (z=3..5), 2 svd (z=3), 3 reg (z=3)
template<int MODE, int AUX, int ASUM>
__global__ __launch_bounds__(256) void gemm_k(
    const unsigned short* __restrict__ A,  long sA,
    const unsigned short* __restrict__ Wt, long sW,
    const float* __restrict__ bias,        long sB,
    const unsigned short* __restrict__ x0, long sX,
    const unsigned short* __restrict__ xl, long sXl,
    unsigned short* __restrict__ outb,     long sO,
    int M, int N, int K,
    const unsigned short* __restrict__ es, float* __restrict__ mbuf,
    float* __restrict__ svb, const float* __restrict__ W3,
    const float* __restrict__ b3, float* __restrict__ outf)
{
    constexpr int SMEMB = (MODE == 3) ? 32768 : 16384;
    __shared__ __align__(16) unsigned char smem[SMEMB];
    int t = threadIdx.x;

    if (AUX && blockIdx.z >= 3) {
        int ablk = (blockIdx.z - 3) * 256 + blockIdx.y * 4 + blockIdx.x;
        if (AUX == 1)      pairsum_dev(es, mbuf, ablk, t, smem);
        else if (AUX == 2) svd_dev(mbuf, svb, ablk, t, smem);
        else               reg_dev(svb, outf, ablk, t, smem);
        return;
    }

    int e = blockIdx.z;
    A    += (size_t)e * sA;
    Wt   += (size_t)e * sW;
    bias += (size_t)e * sB;
    outb += (size_t)e * sO;
    if (MODE == 0) { x0 += (size_t)e * sX; xl += (size_t)e * sXl; }

    unsigned short* As = (unsigned short*)smem;
    unsigned short* Bs = As + 128 * 32;
    int w = t >> 6, lane = t & 63;
    int quad = lane >> 4, lid = lane & 15;
    int wr = (w & 1) * 64, wc = (w >> 1) * 64;
    int rowbase = blockIdx.y * 128, colbase = blockIdx.x * 128;

    int chunk = w * 2;
    int sub = lane >> 2;
    int kk = (lane & 3) * 8;
    const unsigned short* pa0 = A  + (size_t)(rowbase + chunk * 16 + sub) * K + kk;
    const unsigned short* pa1 = pa0 + (size_t)16 * K;
    const unsigned short* pb0 = Wt + (size_t)(colbase + chunk * 16 + sub) * K + kk;
    const unsigned short* pb1 = pb0 + (size_t)16 * K;
    unsigned short* la0 = As + chunk * 512 + lane * 8;
    unsigned short* la1 = la0 + 512;
    unsigned short* lb0 = Bs + chunk * 512 + lane * 8;
    unsigned short* lb1 = lb0 + 512;

    floatx4 acc[4][4];
    #pragma unroll
    for (int i = 0; i < 4; i++)
        #pragma unroll
        for (int j = 0; j < 4; j++) acc[i][j] = {0.f, 0.f, 0.f, 0.f};

    for (int k0 = 0; k0 < K; k0 += 32) {
        if (k0) __syncthreads();
        if (ASUM) {
            sum3st(pa0 + k0, la0);
            sum3st(pa1 + k0, la1);
        } else {
            gld16(pa0 + k0, la0);
            gld16(pa1 + k0, la1);
        }
        gld16(pb0 + k0, lb0);
        gld16(pb1 + k0, lb1);
        __syncthreads();
        short8 af[4], bfr[4];
        #pragma unroll
        for (int i = 0; i < 4; i++) {
            af[i]  = *(const short8*)(As + (wr + i * 16 + lid) * 32 + quad * 8);
            bfr[i] = *(const short8*)(Bs + (wc + i * 16 + lid) * 32 + quad * 8);
        }
        #pragma unroll
        for (int i = 0; i < 4; i++)
            #pragma unroll
            for (int j = 0; j < 4; j++)
                acc[i][j] = __builtin_amdgcn_mfma_f32_16x16x32_bf16(bfr[j], af[i], acc[i][j], 0, 0, 0);
    }

    // Swapped C/D layout: row = wr + i*16 + (lane&15), cols = wc + j*16 + quad*4 + rr
    if (MODE == 3) {
        __syncthreads();                       // As/Bs dead for all waves
        unsigned short* h2s = (unsigned short*)smem;   // [128][128] bf16, XOR-swizzled
        #pragma unroll
        for (int i = 0; i < 4; i++) {
            int rl = wr + i * 16 + lid;
            int sw = (rl & 7) << 3;
            #pragma unroll
            for (int j = 0; j < 4; j++) {
                int col0 = wc + j * 16 + quad * 4;
                float4 bv = *(const float4*)(bias + col0);
                float v0 = fmaxf(acc[i][j][0] + bv.x, 0.f);
                float v1 = fmaxf(acc[i][j][1] + bv.y, 0.f);
                float v2 = fmaxf(acc[i][j][2] + bv.z, 0.f);
                float v3 = fmaxf(acc[i][j][3] + bv.w, 0.f);
                us4 o = { f2bf(v0), f2bf(v1), f2bf(v2), f2bf(v3) };
                *(us4*)(h2s + (size_t)rl * 128 + (col0 ^ sw)) = o;
            }
        }
        __syncthreads();
        if (t < 128) {
            int sw = (t & 7) << 3;
            const unsigned short* hr = h2s + (size_t)t * 128;
            float p = 0.f;
            #pragma unroll
            for (int cc = 0; cc < 128; cc += 4) {
                us4 hv = *(const us4*)(hr + (cc ^ sw));
                float4 wv = *(const float4*)(W3 + cc);
                p += bf2f(hv.x) * wv.x + bf2f(hv.y) * wv.y
                   + bf2f(hv.z) * wv.z + bf2f(hv.w) * wv.w;
            }
            outf[rowbase + t] = 1.0f / (1.0f + expf(-(p + b3[0])));
        }
        return;
    }

    #pragma unroll
    for (int i = 0; i < 4; i++) {
        int row = rowbase + wr + i * 16 + lid;
        #pragma unroll
        for (int j = 0; j < 4; j++) {
            int col0 = colbase + wc + j * 16 + quad * 4;
            size_t off = (size_t)row * N + col0;
            float4 bv = *(const float4*)(bias + col0);
            float v0 = acc[i][j][0] + bv.x;
            float v1 = acc[i][j][1] + bv.y;
            float v2 = acc[i][j][2] + bv.z;
            float v3 = acc[i][j][3] + bv.w;
            if (MODE == 0) {
                us4 xv = *(const us4*)(x0 + off);
                us4 lv = *(const us4*)(xl + off);
                v0 = bf2f(xv.x) * v0 + bf2f(lv.x);
                v1 = bf2f(xv.y) * v1 + bf2f(lv.y);
                v2 = bf2f(xv.z) * v2 + bf2f(lv.z);
                v3 = bf2f(xv.w) * v3 + bf2f(lv.w);
            } else if (MODE == 1) {
                v0 = fmaxf(v0, 0.f) * (1.f / 3.f);
                v1 = fmaxf(v1, 0.f) * (1.f / 3.f);
                v2 = fmaxf(v2, 0.f) * (1.f / 3.f);
                v3 = fmaxf(v3, 0.f) * (1.f / 3.f);
            } else {
                v0 = fmaxf(v0, 0.f);
                v1 = fmaxf(v1, 0.f);
                v2 = fmaxf(v2, 0.f);
                v3 = fmaxf(v3, 0.f);
            }
            us4 o = { f2bf(v0), f2bf(v1), f2bf(v2), f2bf(v3) };
            *(us4*)(outb + off) = o;
        }
    }
}

extern "C" void kernel_launch(void* const* d_in, const int* in_sizes, int n_in,
                              void* d_out, int out_size, void* d_ws, size_t ws_size,
                              hipStream_t stream)
{
    const int*   x      = (const int*)d_in[0];
    const float* emb    = (const float*)d_in[1];
    const float* crossW = (const float*)d_in[2];
    const float* crossb = (const float*)d_in[3];
    const float* mlp1W  = (const float*)d_in[4];
    const float* mlp1b  = (const float*)d_in[5];
    const float* W1     = (const float*)d_in[6];
    const float* b1     = (const float*)d_in[7];
    const float* W2     = (const float*)d_in[8];
    const float* b2     = (const float*)d_in[9];
    const float* W3     = (const float*)d_in[10];
    const float* b3     = (const float*)d_in[11];
    float* out = (float*)d_out;

    unsigned char* wsb = (unsigned char*)d_ws;
    size_t o = 0;
    auto alloc = [&](size_t bytes) -> void* {
        void* p = wsb + o; o += (bytes + 255) & ~(size_t)255; return p;
    };
    unsigned short* esb  = (unsigned short*)alloc(3 * BE_ * 2);
    unsigned short* B0   = (unsigned short*)alloc(3 * BE_ * 2);
    unsigned short* B1   = (unsigned short*)alloc(3 * BE_ * 2);
    unsigned short* WtC  = (unsigned short*)alloc((size_t)12 * 512 * 512 * 2);
    unsigned short* Wt1  = (unsigned short*)alloc((size_t)512 * 256 * 2);
    unsigned short* Wt2  = (unsigned short*)alloc((size_t)256 * 128 * 2);
    float*          mbuf = (float*)alloc(48 * 1024 * 4);
    float*          svb  = (float*)alloc(48 * 32 * 4);
    unsigned short* WtM  = WtC + (size_t)9 * 512 * 512;
    unsigned short* h1b  = esb;       // esb dead after cross3; reuse for h1

    // weights -> bf16 transposed [N][K]
    wtrans12_k<<<dim3(16, 16, 12), 256, 0, stream>>>(crossW, mlp1W, WtC);
    wtrans_k<<<dim3( 8, 16), 256, 0, stream>>>(W1, Wt1, 512, 256);
    wtrans_k<<<dim3( 4,  8), 256, 0, stream>>>(W2, Wt2, 256, 128);

    gather_k<<<(NE_ * B_ * F_ * 4) / 256, 256, 0, stream>>>(x, emb, esb);

    hipMemsetAsync(mbuf, 0, 48 * 1024 * 4, stream);

    const long sW512 = 3 * 512 * 512;   // per-e stride in cross weights

    // cross layer 1  (+ pairsum aux blocks, z=3..5)
    gemm_k<0, 1, 0><<<dim3(4, 64, 6), 256, 0, stream>>>(
        esb, (long)BE_, WtC, sW512, crossb, 3 * 512,
        esb, (long)BE_, esb, (long)BE_, B0, (long)BE_, B_, EOD_, EOD_,
        esb, mbuf, svb, nullptr, nullptr, nullptr);
    // cross layer 2  (+ svd aux blocks, z=3)
    gemm_k<0, 2, 0><<<dim3(4, 64, 4), 256, 0, stream>>>(
        B0, (long)BE_, WtC + 512 * 512, sW512, crossb + 512, 3 * 512,
        esb, (long)BE_, B0, (long)BE_, B1, (long)BE_, B_, EOD_, EOD_,
        nullptr, mbuf, svb, nullptr, nullptr, nullptr);
    // cross layer 3  (+ reg-loss aux block, z=3)
    gemm_k<0, 3, 0><<<dim3(4, 64, 4), 256, 0, stream>>>(
        B1, (long)BE_, WtC + 2 * 512 * 512, sW512, crossb + 1024, 3 * 512,
        esb, (long)BE_, B1, (long)BE_, B0, (long)BE_, B_, EOD_, EOD_,
        nullptr, mbuf, svb, nullptr, nullptr, out);
    // mlp1 per-branch: relu(v)/3 slices
    gemm_k<1, 0, 0><<<dim3(4, 64, 3), 256, 0, stream>>>(
        B0, (long)BE_, WtM, 512 * 512, mlp1b, 512,
        nullptr, 0, nullptr, 0, B1, (long)BE_, B_, M1_, EOD_,
        nullptr, nullptr, nullptr, nullptr, nullptr, nullptr);
    // W1: A = sum of 3 slices (fused sum3), relu
    gemm_k<2, 0, 1><<<dim3(2, 64, 1), 256, 0, stream>>>(
        B1, 0, Wt1, 0, b1, 0, nullptr, 0, nullptr, 0,
        h1b, 0, B_, M2_, M1_,
        nullptr, nullptr, nullptr, nullptr, nullptr, nullptr);
    // W2 + W3 + sigmoid fused
    gemm_k<3, 0, 0><<<dim3(1, 64, 1), 256, 0, stream>>>(
        h1b, 0, Wt2, 0, b2, 0, nullptr, 0, nullptr, 0,
        nullptr, 0, B_, M3_, M2_,
        nullptr, nullptr, nullptr, W3, b3, out);
}

// Round 2
// 664.527 us; speedup vs baseline: 1.0635x; 1.0392x over previous
//
#include <hip/hip_runtime.h>
#include <math.h>

#define B_ 8192
#define F_ 16
#define V_ 50000
#define D_ 32
#define NE_ 3
#define EOD_ 512
#define M1_ 512
#define M2_ 256
#define M3_ 128
#define BE_ ((size_t)B_ * EOD_)

typedef __attribute__((ext_vector_type(8))) short short8;
typedef __attribute__((ext_vector_type(4))) float floatx4;
typedef __attribute__((ext_vector_type(4))) unsigned short us4;

__device__ __forceinline__ unsigned short f2bf(float f) {
    union { float f; unsigned u; } v; v.f = f;
    unsigned r = v.u + 0x7FFF + ((v.u >> 16) & 1);
    return (unsigned short)(r >> 16);
}
__device__ __forceinline__ float bf2f(unsigned short h) {
    union { unsigned u; float f; } v; v.u = (unsigned)h << 16;
    return v.f;
}
// async global->LDS, 16B per lane; LDS dest must be wave-uniform base + lane*16
__device__ __forceinline__ void gld16(const void* g, void* l) {
    __builtin_amdgcn_global_load_lds(
        (const __attribute__((address_space(1))) unsigned int*)g,
        (__attribute__((address_space(3))) unsigned int*)l, 16, 0, 0);
}
// load 3 bf16x8 slices (stride BE_), sum in f32, store 16B to LDS
__device__ __forceinline__ void sum3st(const unsigned short* p, unsigned short* l) {
    uint4 a = *(const uint4*)p;
    uint4 b = *(const uint4*)(p + BE_);
    uint4 c = *(const uint4*)(p + 2 * BE_);
    const unsigned short* pa = (const unsigned short*)&a;
    const unsigned short* pb = (const unsigned short*)&b;
    const unsigned short* pc = (const unsigned short*)&c;
    unsigned short r[8];
    #pragma unroll
    for (int j = 0; j < 8; j++) r[j] = f2bf(bf2f(pa[j]) + bf2f(pb[j]) + bf2f(pc[j]));
    *(uint4*)l = *(uint4*)r;
}

// ================= prep: all weight transposes + gather + mbuf zero, one dispatch ================
__device__ __forceinline__ void wtrans_dev(const float* __restrict__ W,
    unsigned short* __restrict__ Wt, int K, int N, int bx, int by, int t,
    float (*tile)[33])
{
    int bn = bx * 32, bk = by * 32;
    int tx = t & 31, ty = t >> 5;   // 32 x 8
    #pragma unroll
    for (int i = 0; i < 32; i += 8)
        tile[ty + i][tx] = W[(size_t)(bk + ty + i) * N + bn + tx];
    __syncthreads();
    #pragma unroll
    for (int i = 0; i < 32; i += 8)
        Wt[(size_t)(bn + ty + i) * K + bk + tx] = f2bf(tile[tx][ty + i]);
}

__global__ __launch_bounds__(256) void prep_k(
    const int* __restrict__ x, const float* __restrict__ emb,
    const float* __restrict__ crossW, const float* __restrict__ mlp1W,
    const float* __restrict__ W1, const float* __restrict__ W2,
    unsigned short* __restrict__ WtC, unsigned short* __restrict__ Wt1,
    unsigned short* __restrict__ Wt2, unsigned short* __restrict__ esb,
    float* __restrict__ mbuf)
{
    __shared__ float tile[32][33];
    int blk = blockIdx.x;
    int t = threadIdx.x;
    if (blk < 3072) {                                    // 12x 512x512 transposes
        int bx = blk & 15, by = (blk >> 4) & 15, mat = blk >> 8;
        const float* Wm = (mat < 9) ? crossW + (size_t)mat * 512 * 512
                                    : mlp1W + (size_t)(mat - 9) * 512 * 512;
        wtrans_dev(Wm, WtC + (size_t)mat * 512 * 512, 512, 512, bx, by, t, tile);
    } else if (blk < 3200) {                             // W1 512x256
        int r = blk - 3072;
        wtrans_dev(W1, Wt1, 512, 256, r & 7, r >> 3, t, tile);
    } else if (blk < 3232) {                             // W2 256x128
        int r = blk - 3200;
        wtrans_dev(W2, Wt2, 256, 128, r & 3, r >> 2, t, tile);
    } else if (blk < 9376) {                             // embedding gather
        int gid = (blk - 3232) * 256 + t;
        int d8 = gid & 3;
        int f  = (gid >> 2) & 15;
        int b  = (gid >> 6) & (B_ - 1);
        int e  = gid >> 19;
        int idx = x[b * F_ + f] + f * V_;
        const float4* src = (const float4*)(emb + ((size_t)e * F_ * V_ + idx) * D_) + d8 * 2;
        float4 v0 = src[0], v1 = src[1];
        unsigned short o[8];
        o[0] = f2bf(v0.x); o[1] = f2bf(v0.y); o[2] = f2bf(v0.z); o[3] = f2bf(v0.w);
        o[4] = f2bf(v1.x); o[5] = f2bf(v1.y); o[6] = f2bf(v1.z); o[7] = f2bf(v1.w);
        unsigned short* dst = esb + ((size_t)e * B_ + b) * EOD_ + f * D_ + d8 * 8;
        *(uint4*)dst = *(uint4*)o;
    } else {                                             // zero mbuf (48*1024 floats)
        int r = blk - 9376;
        mbuf[(size_t)r * 256 + t] = 0.f;
    }
}

// ---------------- aux device paths (fused as extra z-blocks into GEMMs) ----------------
// pair Gram accumulation (bf16 in, fp32 atomic accum); ablk in [0,768)
__device__ void pairsum_dev(const unsigned short* es, float* m, int ablk, int t,
                            void* smemv)
{
    const int pi[3] = {1, 2, 2};
    const int pj[3] = {0, 0, 1};
    int pk = ablk % 48, by = ablk / 48;
    int pair = pk >> 4, k = pk & 15;
    const unsigned short* Ei = es + (size_t)pi[pair] * BE_ + k * D_;
    const unsigned short* Ej = es + (size_t)pj[pair] * BE_ + k * D_;
    int b0 = by * (B_ / 16);

    float (*sa)[32] = (float(*)[32])smemv;
    float (*sb)[32] = sa + 8;
    int d = t >> 3, e4 = (t & 7) * 4;
    int lr = t >> 5, lc = t & 31;
    float a0 = 0, a1 = 0, a2 = 0, a3 = 0;

    for (int bb = b0; bb < b0 + B_ / 16; bb += 8) {
        __syncthreads();
        sa[lr][lc] = bf2f(Ei[(size_t)(bb + lr) * EOD_ + lc]);
        sb[lr][lc] = bf2f(Ej[(size_t)(bb + lr) * EOD_ + lc]);
        __syncthreads();
        #pragma unroll
        for (int s2 = 0; s2 < 8; s2++) {
            float avv = sa[s2][d];
            float4 bvv = *(const float4*)&sb[s2][e4];
            a0 += avv * bvv.x; a1 += avv * bvv.y;
            a2 += avv * bvv.z; a3 += avv * bvv.w;
        }
    }
    float* dst = m + (size_t)pk * 1024 + d * 32 + e4;
    atomicAdd(dst + 0, a0); atomicAdd(dst + 1, a1);
    atomicAdd(dst + 2, a2); atomicAdd(dst + 3, a3);
}

// 32x32 singular values: one-sided Jacobi, one wave per matrix, register-resident.
// Split into two 3-sweep phases so each hides under a GEMM dispatch.
// PHASE 0: load Gram from mg, 3 sweeps, store column state to st.
// PHASE 1: load state from st, 3 sweeps, write ranked singular values to sv.
template<int PHASE>
__device__ void svd_dev(const float* mg, float* st, float* sv, int ablk, int t,
                        void* smemv)
{
    if (ablk >= 48 || t >= 64) return;
    int mat = ablk;
    int l = t;
    int col = l & 31, half = l >> 5;
    float a[16];
    if (PHASE == 0) {
        const float* src = mg + (size_t)mat * 1024 + half * 16 * 32 + col;
        #pragma unroll
        for (int j = 0; j < 16; j++) a[j] = src[j * 32];
    } else {
        #pragma unroll
        for (int j = 0; j < 16; j++) a[j] = st[(size_t)(mat * 16 + j) * 64 + l];
    }

    for (int sweep = 0; sweep < 3; sweep++) {
        for (int r = 0; r < 31; r++) {
            int partner, isp;
            if (col == 31) { partner = r; isp = 1; }
            else {
                int u = col - r; if (u < 0) u += 31;
                if (u == 0) { partner = 31; isp = 0; }
                else {
                    int v = 2 * r - col; v %= 31; if (v < 0) v += 31;
                    partner = v;
                    isp = (u <= 15) ? 1 : 0;
                }
            }
            int plane = half * 32 + partner;
            float b[16];
            #pragma unroll
            for (int j = 0; j < 16; j++) b[j] = __shfl(a[j], plane, 64);
            float own = 0.f, cross = 0.f, par = 0.f;
            #pragma unroll
            for (int j = 0; j < 16; j++) {
                own   += a[j] * a[j];
                cross += a[j] * b[j];
                par   += b[j] * b[j];
            }
            own   += __shfl_xor(own, 32);
            cross += __shfl_xor(cross, 32);
            par   += __shfl_xor(par, 32);
            float app = isp ? own : par;
            float aqq = isp ? par : own;
            float c = 1.f, s = 0.f;
            if (fabsf(cross) > 1e-12f) {
                float tau = (aqq - app) / (2.f * cross);
                float tt = (tau >= 0.f) ? 1.f / (tau + sqrtf(1.f + tau * tau))
                                        : 1.f / (tau - sqrtf(1.f + tau * tau));
                c = rsqrtf(1.f + tt * tt); s = tt * c;
            }
            float sgn = isp ? -s : s;
            #pragma unroll
            for (int j = 0; j < 16; j++) a[j] = c * a[j] + sgn * b[j];
        }
    }

    if (PHASE == 0) {
        #pragma unroll
        for (int j = 0; j < 16; j++) st[(size_t)(mat * 16 + j) * 64 + l] = a[j];
        return;
    }

    float nn = 0.f;
    #pragma unroll
    for (int j = 0; j < 16; j++) nn += a[j] * a[j];
    nn += __shfl_xor(nn, 32);
    float v = sqrtf(nn);

    float* ev = (float*)smemv;
    if (half == 0) ev[col] = v;
    // single wave: LDS ops complete in program order
    if (half == 0) {
        int rank = 0;
        for (int o2 = 0; o2 < 32; o2++) {
            float w = ev[o2];
            if (w > v || (w == v && o2 < col)) rank++;
        }
        sv[(size_t)mat * 32 + rank] = v;
    }
}

// reg loss reduction (256 threads, one block)
__device__ void reg_dev(const float* sv, float* outf, int ablk, int t, void* smemv)
{
    if (ablk != 0) return;
    float* red = (float*)smemv;
    float val = 0.f;
    if (t < 96) {
        int p = t >> 5, d = t & 31;
        float s = 0;
        #pragma unroll
        for (int k = 0; k < 16; k++) s += sv[(size_t)(p * 16 + k) * 32 + d];
        s *= (1.f / 16.f);
        val = s * s;
    }
    red[t] = val; __syncthreads();
    for (int off = 128; off > 0; off >>= 1) {
        if (t < off) red[t] += red[t + off];
        __syncthreads();
    }
    if (t == 0) outf[B_] = 0.01f * red[0] / 96.f;
}

// ---------------- bf16 MFMA GEMM, 128x128 tile, BK=64, z-batched ----------------
// Swapped-operand MFMA: lane holds 4 CONSECUTIVE COLS of one row -> us4 epilogue.
// MODE 0: v = x0*v + xl  (cross layer)
// MODE 1: v = relu(v)/3  (mlp1 slices)
// MODE 2: v = relu(v)    (W1)
// MODE 3: relu -> LDS -> per-row dot with W3 + sigmoid -> outf (W2+final fused)
// ASUM 1: A-staging sums 3 bf16 slices (stride BE_) instead of gld16
// AUX: 0 none, 1 pairsum, 2 svd phase0, 3 svd phase1, 4 reg  (blocks with z>=3)
template<int MODE, int AUX, int ASUM>
__global__ __launch_bounds__(256) void gemm_k(
    const unsigned short* __restrict__ A,  long sA,
    const unsigned short* __restrict__ Wt, long sW,
    const float* __restrict__ bias,        long sB,
    const unsigned short* __restrict__ x0, long sX,
    const unsigned short* __restrict__ xl, long sXl,
    unsigned short* __restrict__ outb,     long sO,
    int M, int N, int K,
    const unsigned short* __restrict__ es, float* __restrict__ mbuf,
    float* __restrict__ svst, float* __restrict__ svb,
    const float* __restrict__ W3, const float* __restrict__ b3,
    float* __restrict__ outf)
{
    __shared__ __align__(16) unsigned char smem[32768];
    int t = threadIdx.x;

    if (AUX && blockIdx.z >= 3) {
        int ablk = (blockIdx.z - 3) * 256 + blockIdx.y * 4 + blockIdx.x;
        if (AUX == 1)      pairsum_dev(es, mbuf, ablk, t, smem);
        else if (AUX == 2) svd_dev<0>(mbuf, svst, svb, ablk, t, smem);
        else if (AUX == 3) svd_dev<1>(mbuf, svst, svb, ablk, t, smem);
        else               reg_dev(svb, outf, ablk, t, smem);
        return;
    }

    int e = blockIdx.z;
    A    += (size_t)e * sA;
    Wt   += (size_t)e * sW;
    bias += (size_t)e * sB;
    outb += (size_t)e * sO;
    if (MODE == 0) { x0 += (size_t)e * sX; xl += (size_t)e * sXl; }

    unsigned short* As = (unsigned short*)smem;          // [128][64]
    unsigned short* Bs = As + 128 * 64;                  // [128][64]
    int w = t >> 6, lane = t & 63;
    int quad = lane >> 4, lid = lane & 15;
    int wr = (w & 1) * 64, wc = (w >> 1) * 64;
    int rowbase = blockIdx.y * 128, colbase = blockIdx.x * 128;

    int r4 = t >> 3;            // 0..31  (row within 32-row group)
    int c8 = (t & 7) * 8;       // element offset of this thread's 16B chunk
    const unsigned short* Ab = A  + (size_t)rowbase * K + c8;
    const unsigned short* Bb = Wt + (size_t)colbase * K + c8;
    unsigned short* lA = As + t * 8;
    unsigned short* lB = Bs + t * 8;

    floatx4 acc[4][4];
    #pragma unroll
    for (int i = 0; i < 4; i++)
        #pragma unroll
        for (int j = 0; j < 4; j++) acc[i][j] = {0.f, 0.f, 0.f, 0.f};

    for (int k0 = 0; k0 < K; k0 += 64) {
        if (k0) __syncthreads();
        #pragma unroll
        for (int i = 0; i < 4; i++) {
            size_t go = (size_t)(i * 32 + r4) * K + k0;
            if (ASUM) sum3st(Ab + go, lA + i * 2048);
            else      gld16(Ab + go, lA + i * 2048);
            gld16(Bb + go, lB + i * 2048);
        }
        __syncthreads();
        #pragma unroll
        for (int s = 0; s < 2; s++) {
            short8 af[4], bfr[4];
            #pragma unroll
            for (int i = 0; i < 4; i++) {
                af[i]  = *(const short8*)(As + (wr + i * 16 + lid) * 64 + s * 32 + quad * 8);
                bfr[i] = *(const short8*)(Bs + (wc + i * 16 + lid) * 64 + s * 32 + quad * 8);
            }
            #pragma unroll
            for (int i = 0; i < 4; i++)
                #pragma unroll
                for (int j = 0; j < 4; j++)
                    acc[i][j] = __builtin_amdgcn_mfma_f32_16x16x32_bf16(bfr[j], af[i], acc[i][j], 0, 0, 0);
        }
    }

    // Swapped C/D layout: row = wr + i*16 + (lane&15), cols = wc + j*16 + quad*4 + rr
    if (MODE == 3) {
        __syncthreads();                       // As/Bs dead for all waves
        unsigned short* h2s = (unsigned short*)smem;   // [128][128] bf16, XOR-swizzled
        #pragma unroll
        for (int i = 0; i < 4; i++) {
            int rl = wr + i * 16 + lid;
            int sw = (rl & 7) << 3;
            #pragma unroll
            for (int j = 0; j < 4; j++) {
                int col0 = wc + j * 16 + quad * 4;
                float4 bv = *(const float4*)(bias + col0);
                float v0 = fmaxf(acc[i][j][0] + bv.x, 0.f);
                float v1 = fmaxf(acc[i][j][1] + bv.y, 0.f);
                float v2 = fmaxf(acc[i][j][2] + bv.z, 0.f);
                float v3 = fmaxf(acc[i][j][3] + bv.w, 0.f);
                us4 o = { f2bf(v0), f2bf(v1), f2bf(v2), f2bf(v3) };
                *(us4*)(h2s + (size_t)rl * 128 + (col0 ^ sw)) = o;
            }
        }
        __syncthreads();
        if (t < 128) {
            int sw = (t & 7) << 3;
            const unsigned short* hr = h2s + (size_t)t * 128;
            float p = 0.f;
            #pragma unroll
            for (int cc = 0; cc < 128; cc += 4) {
                us4 hv = *(const us4*)(hr + (cc ^ sw));
                float4 wv = *(const float4*)(W3 + cc);
                p += bf2f(hv.x) * wv.x + bf2f(hv.y) * wv.y
                   + bf2f(hv.z) * wv.z + bf2f(hv.w) * wv.w;
            }
            outf[rowbase + t] = 1.0f / (1.0f + expf(-(p + b3[0])));
        }
        return;
    }

    #pragma unroll
    for (int i = 0; i < 4; i++) {
        int row = rowbase + wr + i * 16 + lid;
        #pragma unroll
        for (int j = 0; j < 4; j++) {
            int col0 = colbase + wc + j * 16 + quad * 4;
            size_t off = (size_t)row * N + col0;
            float4 bv = *(const float4*)(bias + col0);
            float v0 = acc[i][j][0] + bv.x;
            float v1 = acc[i][j][1] + bv.y;
            float v2 = acc[i][j][2] + bv.z;
            float v3 = acc[i][j][3] + bv.w;
            if (MODE == 0) {
                us4 xv = *(const us4*)(x0 + off);
                us4 lv = *(const us4*)(xl + off);
                v0 = bf2f(xv.x) * v0 + bf2f(lv.x);
                v1 = bf2f(xv.y) * v1 + bf2f(lv.y);
                v2 = bf2f(xv.z) * v2 + bf2f(lv.z);
                v3 = bf2f(xv.w) * v3 + bf2f(lv.w);
            } else if (MODE == 1) {
                v0 = fmaxf(v0, 0.f) * (1.f / 3.f);
                v1 = fmaxf(v1, 0.f) * (1.f / 3.f);
                v2 = fmaxf(v2, 0.f) * (1.f / 3.f);
                v3 = fmaxf(v3, 0.f) * (1.f / 3.f);
            } else {
                v0 = fmaxf(v0, 0.f);
                v1 = fmaxf(v1, 0.f);
                v2 = fmaxf(v2, 0.f);
                v3 = fmaxf(v3, 0.f);
            }
            us4 o = { f2bf(v0), f2bf(v1), f2bf(v2), f2bf(v3) };
            *(us4*)(outb + off) = o;
        }
    }
}

extern "C" void kernel_launch(void* const* d_in, const int* in_sizes, int n_in,
                              void* d_out, int out_size, void* d_ws, size_t ws_size,
                              hipStream_t stream)
{
    const int*   x      = (const int*)d_in[0];
    const float* emb    = (const float*)d_in[1];
    const float* crossW = (const float*)d_in[2];
    const float* crossb = (const float*)d_in[3];
    const float* mlp1W  = (const float*)d_in[4];
    const float* mlp1b  = (const float*)d_in[5];
    const float* W1     = (const float*)d_in[6];
    const float* b1     = (const float*)d_in[7];
    const float* W2     = (const float*)d_in[8];
    const float* b2     = (const float*)d_in[9];
    const float* W3     = (const float*)d_in[10];
    const float* b3     = (const float*)d_in[11];
    float* out = (float*)d_out;

    unsigned char* wsb = (unsigned char*)d_ws;
    size_t o = 0;
    auto alloc = [&](size_t bytes) -> void* {
        void* p = wsb + o; o += (bytes + 255) & ~(size_t)255; return p;
    };
    unsigned short* esb  = (unsigned short*)alloc(3 * BE_ * 2);
    unsigned short* B0   = (unsigned short*)alloc(3 * BE_ * 2);
    unsigned short* B1   = (unsigned short*)alloc(3 * BE_ * 2);
    unsigned short* WtC  = (unsigned short*)alloc((size_t)12 * 512 * 512 * 2);
    unsigned short* Wt1  = (unsigned short*)alloc((size_t)512 * 256 * 2);
    unsigned short* Wt2  = (unsigned short*)alloc((size_t)256 * 128 * 2);
    float*          mbuf = (float*)alloc(48 * 1024 * 4);
    float*          svst = (float*)alloc(48 * 16 * 64 * 4);
    float*          svb  = (float*)alloc(48 * 32 * 4);
    unsigned short* WtM  = WtC + (size_t)9 * 512 * 512;
    unsigned short* h1b  = esb;       // esb dead after cross3; reuse for h1

    // all preprocessing (12+2 weight transposes, gather, mbuf zero) in one dispatch
    prep_k<<<9568, 256, 0, stream>>>(x, emb, crossW, mlp1W, W1, W2,
                                     WtC, Wt1, Wt2, esb, mbuf);

    const long sW512 = 3 * 512 * 512;   // per-e stride in cross weights

    // cross layer 1  (+ pairsum aux blocks, z=3..5)
    gemm_k<0, 1, 0><<<dim3(4, 64, 6), 256, 0, stream>>>(
        esb, (long)BE_, WtC, sW512, crossb, 3 * 512,
        esb, (long)BE_, esb, (long)BE_, B0, (long)BE_, B_, EOD_, EOD_,
        esb, mbuf, svst, svb, nullptr, nullptr, nullptr);
    // cross layer 2  (+ svd phase-0 aux, z=3)
    gemm_k<0, 2, 0><<<dim3(4, 64, 4), 256, 0, stream>>>(
        B0, (long)BE_, WtC + 512 * 512, sW512, crossb + 512, 3 * 512,
        esb, (long)BE_, B0, (long)BE_, B1, (long)BE_, B_, EOD_, EOD_,
        nullptr, mbuf, svst, svb, nullptr, nullptr, nullptr);
    // cross layer 3  (+ svd phase-1 aux, z=3)
    gemm_k<0, 3, 0><<<dim3(4, 64, 4), 256, 0, stream>>>(
        B1, (long)BE_, WtC + 2 * 512 * 512, sW512, crossb + 1024, 3 * 512,
        esb, (long)BE_, B1, (long)BE_, B0, (long)BE_, B_, EOD_, EOD_,
        nullptr, mbuf, svst, svb, nullptr, nullptr, nullptr);
    // mlp1 per-branch: relu(v)/3 slices  (+ reg-loss aux, z=3)
    gemm_k<1, 4, 0><<<dim3(4, 64, 4), 256, 0, stream>>>(
        B0, (long)BE_, WtM, 512 * 512, mlp1b, 512,
        nullptr, 0, nullptr, 0, B1, (long)BE_, B_, M1_, EOD_,
        nullptr, mbuf, svst, svb, nullptr, nullptr, out);
    // W1: A = sum of 3 slices (fused sum3), relu
    gemm_k<2, 0, 1><<<dim3(2, 64, 1), 256, 0, stream>>>(
        B1, 0, Wt1, 0, b1, 0, nullptr, 0, nullptr, 0,
        h1b, 0, B_, M2_, M1_,
        nullptr, nullptr, nullptr, nullptr, nullptr, nullptr, nullptr);
    // W2 + W3 + sigmoid fused
    gemm_k<3, 0, 0><<<dim3(1, 64, 1), 256, 0, stream>>>(
        h1b, 0, Wt2, 0, b2, 0, nullptr, 0, nullptr, 0,
        nullptr, 0, B_, M3_, M2_,
        nullptr, nullptr, nullptr, nullptr, W3, b3, out);
}